// Round 3
// baseline (174.247 us; speedup 1.0000x reference)
//
#include <hip/hip_runtime.h>
#include <cstdint>
#include <cstddef>

// Problem constants
#define B_    128   // batch
#define C_    32    // in channels
#define O_    64    // out channels
#define H_    34    // input H=W (34 = 32+2)
#define NPOS  1024  // 32*32 spatial positions
#define K9    9     // 3x3 taps
#define BC    (B_ * C_)   // 4096
#define BO    (B_ * O_)   // 8192
#define NPK   (NPOS * K9) // 9216 floats per (o,c) weight row

typedef __bf16 v8bf __attribute__((ext_vector_type(8)));
typedef float  v4f  __attribute__((ext_vector_type(4)));
typedef float  f4a  __attribute__((ext_vector_type(4)));              // 16-B aligned float4

__device__ __forceinline__ unsigned short f2bf(float f) {
    union { float f; unsigned int u; } v; v.f = f;
    unsigned int u = v.u;
    return (unsigned short)((u + 0x7FFFu + ((u >> 16) & 1u)) >> 16);
}

// ---------------------------------------------------------------------------
// Pass 1: repack x (fp32 [b][c][34][34]) -> x2 (bf16 [h][w][b][c]).
// Block = (b-pair, h-pair); 272-B contiguous reads per (b,c), float2 loads,
// transposed LDS tile, ushort2 stores.  [unchanged]
// ---------------------------------------------------------------------------
__global__ __launch_bounds__(256) void repack_x(const float* __restrict__ x,
                                                unsigned short* __restrict__ x2) {
    const int bq = blockIdx.x / 17;      // b-pair 0..63
    const int hp = blockIdx.x % 17;      // h-pair 0..16
    const int b0 = bq * 2;
    const int h0 = hp * 2;
    __shared__ unsigned short tile[2][H_][66];   // [hh][w][bb*32+c] (+2 pad)
    const int t = threadIdx.x;

    for (int e = t; e < 2176; e += 256) {
        const int bb  = e / 1088;
        const int rem = e % 1088;
        const int c   = rem / 34;
        const int wp  = rem % 34;        // float2 index within the 68-float run
        const float2 v = *(const float2*)(x +
            ((size_t)((b0 + bb) * C_ + c) * H_ + h0) * H_ + wp * 2);
        const int hh = (wp >= 17) ? 1 : 0;
        const int w  = wp * 2 - hh * 34;
        const int idx = bb * 32 + c;
        tile[hh][w][idx]     = f2bf(v.x);
        tile[hh][w + 1][idx] = f2bf(v.y);
    }
    __syncthreads();

    for (int e = t; e < 2176; e += 256) {
        const int hh  = e / 1088;
        const int rem = e % 1088;
        const int w   = rem >> 5;
        const int i2  = rem & 31;
        ushort2 pk;
        pk.x = tile[hh][w][i2 * 2];
        pk.y = tile[hh][w][i2 * 2 + 1];
        *(ushort2*)(x2 + (size_t)((h0 + hh) * H_ + w) * BC + bq * 64 + i2 * 2) = pk;
    }
}

// ---------------------------------------------------------------------------
// Main (v4): block = (i, j-octet, o-quarter of 16, b-half of 64).
// Grid 1024, LDS 36,864 B -> 4 blocks/CU resident (16 waves/CU, 50% occ);
// co-resident blocks overlap stage<->compute phases naturally.
// Two jj-half phases per block: stage jj 0..3 taps into Wl (36 rows x 512 p,
// XOR-swizzled: elem (d,pl) at d*512 + ((pl>>3)^((d>>2)&7))*8 + (pl&7)),
// compute, barrier, repeat for jj 4..7.
// Staging per phase: 18 (pl,d4) tasks/thread in 2 groups of 9 independent
// dwordx4 loads (all in flight before the vmcnt wait) -> 2 latency
// exposures/phase instead of 9.
// bh-siblings (lb xor 1) are dispatch-adjacent on the same XCD -> second
// read of the shared 147 KB weight slice is an L2 hit.
// Epilogue: direct fp32 out[b][o][pos] + bias; 32-B aligned 32-B runs.
// ---------------------------------------------------------------------------
__global__ __launch_bounds__(256, 4) void lc_fused3(const unsigned short* __restrict__ x2,
                                                    const float* __restrict__ weight,
                                                    const float* __restrict__ bias,
                                                    float* __restrict__ out) {
    __shared__ __align__(16) unsigned short Wl[36 * 512];  // 36,864 B

    const int bid = blockIdx.x;
    const int lb  = (bid & 7) * 128 + (bid >> 3);  // bijective (1024 % 8 == 0)
    const int i   = lb >> 5;           // 0..31
    const int jq  = (lb >> 3) & 3;     // 0..3  (8-j octet)
    const int oq  = (lb >> 1) & 3;     // 0..3  (16-o quarter)
    const int bh  = lb & 1;            // 0..1  (64-b half)
    const int j0  = jq * 8;
    const int o0  = oq * 16;
    const int posbase = i * 32 + j0;   // multiple of 8 -> 32-B aligned out runs
    const int t = threadIdx.x;

    const int wv = t >> 6;      // wave -> 16-b band
    const int l  = t & 63;
    const int lm = l & 15;      // o_local (B n-index) / A m-index (b)
    const int q  = l >> 4;

    v4f acc[8];                 // [jj] (one 16-b m-tile per wave)
#pragma unroll
    for (int a = 0; a < 8; ++a) acc[a] = (v4f){0.f, 0.f, 0.f, 0.f};

    const float* wbase = weight + ((size_t)(o0 * C_) * NPOS + posbase) * K9;

#pragma unroll
    for (int jjh = 0; jjh < 2; ++jjh) {
        // ---- stage: 512 pl x 36 floats (4 jj x 9 taps), 4608 dwordx4 tasks
        const float* wb = wbase + jjh * 36;
#pragma unroll
        for (int g = 0; g < 2; ++g) {
            f4a v[9];
#pragma unroll
            for (int r = 0; r < 9; ++r) {
                const int idx = (g * 9 + r) * 256 + t;   // 0..4607
                const int pl  = idx / 9;
                const int d4  = idx % 9;
                v[r] = *(const f4a*)(wb + (size_t)pl * NPK + d4 * 4);
            }
#pragma unroll
            for (int r = 0; r < 9; ++r) {
                const int idx = (g * 9 + r) * 256 + t;
                const int pl  = idx / 9;
                const int d4  = idx % 9;
                const int col = ((pl >> 3) ^ (d4 & 7)) * 8 + (pl & 7);
#pragma unroll
                for (int u = 0; u < 4; ++u)
                    Wl[(d4 * 4 + u) * 512 + col] = f2bf(v[r][u]);
            }
        }
        __syncthreads();

        // ---- compute: jj_local 0..3 (global jj = jjh*4 + jj_local) ----
#pragma unroll
        for (int kh = 0; kh < 3; ++kh) {
            v8bf ax[6];
            const int rowbase = (i + kh) * H_ + j0 + jjh * 4;
#pragma unroll
            for (int w6 = 0; w6 < 6; ++w6) {
                const unsigned short* xrow = x2 + (size_t)(rowbase + w6) * BC;
                ax[w6] = *(const v8bf*)(xrow + (bh * 64 + wv * 16 + lm) * C_ + q * 8);
            }
#pragma unroll
            for (int kw = 0; kw < 3; ++kw) {
                const int tap = kh * 3 + kw;
#pragma unroll
                for (int jj = 0; jj < 4; ++jj) {
                    const int jk = jj * K9 + tap;        // local row 0..35
                    const int gc = ((lm * 4 + q) ^ ((jk >> 2) & 7)) * 8;
                    const v8bf bfr = *(const v8bf*)&Wl[jk * 512 + gc];
                    acc[jjh * 4 + jj] = __builtin_amdgcn_mfma_f32_16x16x32_bf16(
                        ax[kw + jj], bfr, acc[jjh * 4 + jj], 0, 0, 0);
                }
            }
        }
        if (jjh == 0) __syncthreads();   // Wl reads done before phase-2 stage
    }

    // ---- epilogue: fp32 out + bias; 32-B runs per (b,o) ----
    // D layout: col = lane&15 = o_local, row = q*4 + reg = b_local
    const float* bp = bias + (size_t)(o0 + lm) * NPOS + posbase;
    const f4a bv0 = *(const f4a*)bp;
    const f4a bv1 = *(const f4a*)(bp + 4);
#pragma unroll
    for (int r2 = 0; r2 < 4; ++r2) {
        const int b = bh * 64 + wv * 16 + q * 4 + r2;
        float* op = out + ((size_t)b * O_ + (o0 + lm)) * NPOS + posbase;
        f4a lo = {acc[0][r2] + bv0[0], acc[1][r2] + bv0[1],
                  acc[2][r2] + bv0[2], acc[3][r2] + bv0[3]};
        f4a hi = {acc[4][r2] + bv1[0], acc[5][r2] + bv1[1],
                  acc[6][r2] + bv1[2], acc[7][r2] + bv1[3]};
        *(f4a*)op       = lo;
        *(f4a*)(op + 4) = hi;
    }
}

// ---------------------------------------------------------------------------
// Fallback (no workspace): per-pos kernel gathering straight from fp32.
// ---------------------------------------------------------------------------
__global__ __launch_bounds__(256) void lc_fallback(const float* __restrict__ x,
                                                   const float* __restrict__ weight,
                                                   const float* __restrict__ bias,
                                                   float* __restrict__ out) {
    const int pos = blockIdx.x;
    const int i = pos >> 5, j = pos & 31;
    const int t  = threadIdx.x;
    const int wv = t >> 6;
    const int l  = t & 63;
    const int lm = l & 15;
    const int q  = l >> 4;

    float bv[4];
#pragma unroll
    for (int nt = 0; nt < 4; ++nt)
        bv[nt] = bias[(size_t)(nt * 16 + lm) * NPOS + pos];

    v4f acc[2][4];
#pragma unroll
    for (int a = 0; a < 2; ++a)
#pragma unroll
        for (int n = 0; n < 4; ++n) acc[a][n] = (v4f){0.f, 0.f, 0.f, 0.f};

    for (int k = 0; k < K9; ++k) {
        const int kh = k / 3, kw = k % 3;
        v8bf af[2], bfr[4];
#pragma unroll
        for (int mt = 0; mt < 2; ++mt) {
            const int b = wv * 32 + mt * 16 + lm;
            union { v8bf v; unsigned short s[8]; } u;
#pragma unroll
            for (int cc = 0; cc < 8; ++cc)
                u.s[cc] = f2bf(x[(((size_t)b * C_ + q * 8 + cc) * H_ + (i + kh)) * H_ + (j + kw)]);
            af[mt] = u.v;
        }
#pragma unroll
        for (int nt = 0; nt < 4; ++nt) {
            union { v8bf v; unsigned short s[8]; } u;
#pragma unroll
            for (int cc = 0; cc < 8; ++cc) {
                const int p = (nt * 16 + lm) * C_ + q * 8 + cc;
                u.s[cc] = f2bf(weight[((size_t)p * NPOS + pos) * K9 + k]);
            }
            bfr[nt] = u.v;
        }
#pragma unroll
        for (int mt = 0; mt < 2; ++mt)
#pragma unroll
            for (int nt = 0; nt < 4; ++nt)
                acc[mt][nt] = __builtin_amdgcn_mfma_f32_16x16x32_bf16(
                    af[mt], bfr[nt], acc[mt][nt], 0, 0, 0);
    }
#pragma unroll
    for (int mt = 0; mt < 2; ++mt)
#pragma unroll
        for (int nt = 0; nt < 4; ++nt) {
            const int o = nt * 16 + lm;
#pragma unroll
            for (int r = 0; r < 4; ++r) {
                const int b = wv * 32 + mt * 16 + q * 4 + r;
                out[(size_t)(b * O_ + o) * NPOS + pos] = acc[mt][nt][r] + bv[nt];
            }
        }
}

// ---------------------------------------------------------------------------
extern "C" void kernel_launch(void* const* d_in, const int* in_sizes, int n_in,
                              void* d_out, int out_size, void* d_ws, size_t ws_size,
                              hipStream_t stream) {
    const float* x      = (const float*)d_in[0];
    const float* weight = (const float*)d_in[1];
    const float* bias   = (const float*)d_in[2];
    float* out          = (float*)d_out;

    const size_t X2B = (size_t)H_ * H_ * BC * sizeof(unsigned short);     // 9,469,952

    if (ws_size >= X2B) {
        unsigned short* x2 = (unsigned short*)d_ws;
        repack_x<<<64 * 17, 256, 0, stream>>>(x, x2);
        lc_fused3<<<1024, 256, 0, stream>>>(x2, weight, bias, out);
    } else {
        lc_fallback<<<NPOS, 256, 0, stream>>>(x, weight, bias, out);
    }
}

// Round 4
// 164.156 us; speedup vs baseline: 1.0615x; 1.0615x over previous
//
#include <hip/hip_runtime.h>
#include <cstdint>
#include <cstddef>

// Problem constants
#define B_    128   // batch
#define C_    32    // in channels
#define O_    64    // out channels
#define H_    34    // input H=W (34 = 32+2)
#define NPOS  1024  // 32*32 spatial positions
#define K9    9     // 3x3 taps
#define BC    (B_ * C_)   // 4096
#define BO    (B_ * O_)   // 8192
#define NPK   (NPOS * K9) // 9216 floats per (o,c) weight row

typedef __bf16 v8bf __attribute__((ext_vector_type(8)));
typedef float  v4f  __attribute__((ext_vector_type(4)));
typedef float  f4a  __attribute__((ext_vector_type(4)));              // 16-B aligned float4

__device__ __forceinline__ unsigned short f2bf(float f) {
    union { float f; unsigned int u; } v; v.f = f;
    unsigned int u = v.u;
    return (unsigned short)((u + 0x7FFFu + ((u >> 16) & 1u)) >> 16);
}

// ---------------------------------------------------------------------------
// Pass 1: repack x (fp32 [b][c][34][34]) -> x2 (bf16 [h][w][b][c]).
// Block = (b-pair, h-pair); 272-B contiguous reads per (b,c), float2 loads,
// transposed LDS tile, ushort2 stores.  [unchanged]
// ---------------------------------------------------------------------------
__global__ __launch_bounds__(256) void repack_x(const float* __restrict__ x,
                                                unsigned short* __restrict__ x2) {
    const int bq = blockIdx.x / 17;      // b-pair 0..63
    const int hp = blockIdx.x % 17;      // h-pair 0..16
    const int b0 = bq * 2;
    const int h0 = hp * 2;
    __shared__ unsigned short tile[2][H_][66];   // [hh][w][bb*32+c] (+2 pad)
    const int t = threadIdx.x;

    for (int e = t; e < 2176; e += 256) {
        const int bb  = e / 1088;
        const int rem = e % 1088;
        const int c   = rem / 34;
        const int wp  = rem % 34;        // float2 index within the 68-float run
        const float2 v = *(const float2*)(x +
            ((size_t)((b0 + bb) * C_ + c) * H_ + h0) * H_ + wp * 2);
        const int hh = (wp >= 17) ? 1 : 0;
        const int w  = wp * 2 - hh * 34;
        const int idx = bb * 32 + c;
        tile[hh][w][idx]     = f2bf(v.x);
        tile[hh][w + 1][idx] = f2bf(v.y);
    }
    __syncthreads();

    for (int e = t; e < 2176; e += 256) {
        const int hh  = e / 1088;
        const int rem = e % 1088;
        const int w   = rem >> 5;
        const int i2  = rem & 31;
        ushort2 pk;
        pk.x = tile[hh][w][i2 * 2];
        pk.y = tile[hh][w][i2 * 2 + 1];
        *(ushort2*)(x2 + (size_t)((h0 + hh) * H_ + w) * BC + bq * 64 + i2 * 2) = pk;
    }
}

// ---------------------------------------------------------------------------
// Main (v5): v2 geometry (512 blocks = i x j-octet x o-quarter, FULL 128 b,
// each weight byte staged exactly once) + two jj-half phases so LDS = 36
// rows x 512 = 36,864 B -> 4 blocks/CU resident (16 waves/CU), doubling TLP
// to cover the strided weight-gather latency.  Staging volume per block is
// UNCHANGED vs v2 (lesson from v3/v4: never replicate weight staging).
// Per phase: 4608 dwordx4 tasks as 2304 pl-pair tasks (9/thread) in 2
// deep-MLP groups; LDS writes are 4-B ushort2 with the XOR-swizzled column
// (elem (d,pl) at d*512 + ((pl>>3)^((d>>2)&7))*8 + (pl&7)) -> ~2-way banks.
// Chunked XCD map lb=(bid&7)*64+bid>>3: jq-siblings share out 64-B lines on
// one XCD (write-merge in L2), i-siblings share x2 rows.
// Epilogue: direct fp32 out[b][o][pos] + bias; 32-B aligned 32-B runs.
// ---------------------------------------------------------------------------
__global__ __launch_bounds__(256, 4) void lc_fused4(const unsigned short* __restrict__ x2,
                                                    const float* __restrict__ weight,
                                                    const float* __restrict__ bias,
                                                    float* __restrict__ out) {
    __shared__ __align__(16) unsigned short Wl[36 * 512];  // 36,864 B

    const int bid = blockIdx.x;
    const int lb  = (bid & 7) * 64 + (bid >> 3);   // bijective (512 % 8 == 0)
    const int i   = lb >> 4;           // 0..31
    const int jq  = (lb >> 2) & 3;     // 0..3  (8-j octet)
    const int oq  = lb & 3;            // 0..3  (16-o quarter)
    const int j0  = jq * 8;
    const int o0  = oq * 16;
    const int posbase = i * 32 + j0;   // multiple of 8 -> 32-B aligned out runs
    const int t = threadIdx.x;

    const int wv = t >> 6;      // wave -> 32-b band
    const int l  = t & 63;
    const int lm = l & 15;      // o_local (B n-index) / A m-index (b)
    const int q  = l >> 4;

    v4f acc[8][2];              // [jj global][mt]
#pragma unroll
    for (int a = 0; a < 8; ++a)
#pragma unroll
        for (int m = 0; m < 2; ++m) acc[a][m] = (v4f){0.f, 0.f, 0.f, 0.f};

    const float* wbase = weight + ((size_t)(o0 * C_) * NPOS + posbase) * K9;

#pragma unroll
    for (int jjh = 0; jjh < 2; ++jjh) {
        // ---- stage half: 512 pl x 36 floats; 2304 pl-pair tasks (9/thread)
        const float* wb = wbase + jjh * 36;
        // group A: tasks r=0..3 (8 loads), group B: tasks r=4..8 (10 loads)
        f4a va[4][2];
#pragma unroll
        for (int r = 0; r < 4; ++r) {
            const int idx = r * 256 + t;          // task id
            const int plp = idx / 9;              // pl-pair 0..255
            const int d4  = idx % 9;
            va[r][0] = *(const f4a*)(wb + (size_t)(plp * 2)     * NPK + d4 * 4);
            va[r][1] = *(const f4a*)(wb + (size_t)(plp * 2 + 1) * NPK + d4 * 4);
        }
        f4a vb[5][2];
#pragma unroll
        for (int r = 0; r < 5; ++r) {
            const int idx = (r + 4) * 256 + t;
            const int plp = idx / 9;
            const int d4  = idx % 9;
            vb[r][0] = *(const f4a*)(wb + (size_t)(plp * 2)     * NPK + d4 * 4);
            vb[r][1] = *(const f4a*)(wb + (size_t)(plp * 2 + 1) * NPK + d4 * 4);
        }
#pragma unroll
        for (int r = 0; r < 4; ++r) {
            const int idx = r * 256 + t;
            const int plp = idx / 9;
            const int d4  = idx % 9;
            const int col = (((plp >> 2) ^ (d4 & 7)) << 3) + ((plp & 3) << 1);
#pragma unroll
            for (int u = 0; u < 4; ++u) {
                ushort2 pk; pk.x = f2bf(va[r][0][u]); pk.y = f2bf(va[r][1][u]);
                *(ushort2*)&Wl[(d4 * 4 + u) * 512 + col] = pk;
            }
        }
#pragma unroll
        for (int r = 0; r < 5; ++r) {
            const int idx = (r + 4) * 256 + t;
            const int plp = idx / 9;
            const int d4  = idx % 9;
            const int col = (((plp >> 2) ^ (d4 & 7)) << 3) + ((plp & 3) << 1);
#pragma unroll
            for (int u = 0; u < 4; ++u) {
                ushort2 pk; pk.x = f2bf(vb[r][0][u]); pk.y = f2bf(vb[r][1][u]);
                *(ushort2*)&Wl[(d4 * 4 + u) * 512 + col] = pk;
            }
        }
        __syncthreads();

        // ---- compute: jj_local 0..3 (global jj = jjh*4 + jj_local) ----
#pragma unroll
        for (int kh = 0; kh < 3; ++kh) {
            v8bf ax[6][2];
            const int rowbase = (i + kh) * H_ + j0 + jjh * 4;
#pragma unroll
            for (int w6 = 0; w6 < 6; ++w6) {
                const unsigned short* xrow = x2 + (size_t)(rowbase + w6) * BC;
                ax[w6][0] = *(const v8bf*)(xrow + (wv * 32 + lm) * C_ + q * 8);
                ax[w6][1] = *(const v8bf*)(xrow + (wv * 32 + 16 + lm) * C_ + q * 8);
            }
#pragma unroll
            for (int kw = 0; kw < 3; ++kw) {
                const int tap = kh * 3 + kw;
#pragma unroll
                for (int jj = 0; jj < 4; ++jj) {
                    const int jk = jj * K9 + tap;        // local row 0..35
                    const int gc = ((lm * 4 + q) ^ ((jk >> 2) & 7)) * 8;
                    const v8bf bfr = *(const v8bf*)&Wl[jk * 512 + gc];
                    acc[jjh * 4 + jj][0] = __builtin_amdgcn_mfma_f32_16x16x32_bf16(
                        ax[kw + jj][0], bfr, acc[jjh * 4 + jj][0], 0, 0, 0);
                    acc[jjh * 4 + jj][1] = __builtin_amdgcn_mfma_f32_16x16x32_bf16(
                        ax[kw + jj][1], bfr, acc[jjh * 4 + jj][1], 0, 0, 0);
                }
            }
        }
        if (jjh == 0) __syncthreads();   // Wl reads done before phase-2 stage
    }

    // ---- epilogue: fp32 out + bias; 32-B runs per (b,o) ----
    // D layout: col = lane&15 = o_local, row = q*4 + reg = b_local
    const float* bp = bias + (size_t)(o0 + lm) * NPOS + posbase;
    const f4a bv0 = *(const f4a*)bp;
    const f4a bv1 = *(const f4a*)(bp + 4);
#pragma unroll
    for (int mt = 0; mt < 2; ++mt) {
#pragma unroll
        for (int r2 = 0; r2 < 4; ++r2) {
            const int b = wv * 32 + mt * 16 + q * 4 + r2;
            float* op = out + ((size_t)b * O_ + (o0 + lm)) * NPOS + posbase;
            f4a lo = {acc[0][mt][r2] + bv0[0], acc[1][mt][r2] + bv0[1],
                      acc[2][mt][r2] + bv0[2], acc[3][mt][r2] + bv0[3]};
            f4a hi = {acc[4][mt][r2] + bv1[0], acc[5][mt][r2] + bv1[1],
                      acc[6][mt][r2] + bv1[2], acc[7][mt][r2] + bv1[3]};
            *(f4a*)op       = lo;
            *(f4a*)(op + 4) = hi;
        }
    }
}

// ---------------------------------------------------------------------------
// Fallback (no workspace): per-pos kernel gathering straight from fp32.
// ---------------------------------------------------------------------------
__global__ __launch_bounds__(256) void lc_fallback(const float* __restrict__ x,
                                                   const float* __restrict__ weight,
                                                   const float* __restrict__ bias,
                                                   float* __restrict__ out) {
    const int pos = blockIdx.x;
    const int i = pos >> 5, j = pos & 31;
    const int t  = threadIdx.x;
    const int wv = t >> 6;
    const int l  = t & 63;
    const int lm = l & 15;
    const int q  = l >> 4;

    float bv[4];
#pragma unroll
    for (int nt = 0; nt < 4; ++nt)
        bv[nt] = bias[(size_t)(nt * 16 + lm) * NPOS + pos];

    v4f acc[2][4];
#pragma unroll
    for (int a = 0; a < 2; ++a)
#pragma unroll
        for (int n = 0; n < 4; ++n) acc[a][n] = (v4f){0.f, 0.f, 0.f, 0.f};

    for (int k = 0; k < K9; ++k) {
        const int kh = k / 3, kw = k % 3;
        v8bf af[2], bfr[4];
#pragma unroll
        for (int mt = 0; mt < 2; ++mt) {
            const int b = wv * 32 + mt * 16 + lm;
            union { v8bf v; unsigned short s[8]; } u;
#pragma unroll
            for (int cc = 0; cc < 8; ++cc)
                u.s[cc] = f2bf(x[(((size_t)b * C_ + q * 8 + cc) * H_ + (i + kh)) * H_ + (j + kw)]);
            af[mt] = u.v;
        }
#pragma unroll
        for (int nt = 0; nt < 4; ++nt) {
            union { v8bf v; unsigned short s[8]; } u;
#pragma unroll
            for (int cc = 0; cc < 8; ++cc) {
                const int p = (nt * 16 + lm) * C_ + q * 8 + cc;
                u.s[cc] = f2bf(weight[((size_t)p * NPOS + pos) * K9 + k]);
            }
            bfr[nt] = u.v;
        }
#pragma unroll
        for (int mt = 0; mt < 2; ++mt)
#pragma unroll
            for (int nt = 0; nt < 4; ++nt)
                acc[mt][nt] = __builtin_amdgcn_mfma_f32_16x16x32_bf16(
                    af[mt], bfr[nt], acc[mt][nt], 0, 0, 0);
    }
#pragma unroll
    for (int mt = 0; mt < 2; ++mt)
#pragma unroll
        for (int nt = 0; nt < 4; ++nt) {
            const int o = nt * 16 + lm;
#pragma unroll
            for (int r = 0; r < 4; ++r) {
                const int b = wv * 32 + mt * 16 + q * 4 + r;
                out[(size_t)(b * O_ + o) * NPOS + pos] = acc[mt][nt][r] + bv[nt];
            }
        }
}

// ---------------------------------------------------------------------------
extern "C" void kernel_launch(void* const* d_in, const int* in_sizes, int n_in,
                              void* d_out, int out_size, void* d_ws, size_t ws_size,
                              hipStream_t stream) {
    const float* x      = (const float*)d_in[0];
    const float* weight = (const float*)d_in[1];
    const float* bias   = (const float*)d_in[2];
    float* out          = (float*)d_out;

    const size_t X2B = (size_t)H_ * H_ * BC * sizeof(unsigned short);     // 9,469,952

    if (ws_size >= X2B) {
        unsigned short* x2 = (unsigned short*)d_ws;
        repack_x<<<64 * 17, 256, 0, stream>>>(x, x2);
        lc_fused4<<<512, 256, 0, stream>>>(x2, weight, bias, out);
    } else {
        lc_fallback<<<NPOS, 256, 0, stream>>>(x, weight, bias, out);
    }
}

// Round 5
// 158.763 us; speedup vs baseline: 1.0975x; 1.0340x over previous
//
#include <hip/hip_runtime.h>
#include <cstdint>
#include <cstddef>

// Problem constants
#define B_    128   // batch
#define C_    32    // in channels
#define O_    64    // out channels
#define H_    34    // input H=W (34 = 32+2)
#define NPOS  1024  // 32*32 spatial positions
#define K9    9     // 3x3 taps
#define BC    (B_ * C_)   // 4096
#define BO    (B_ * O_)   // 8192
#define NPK   (NPOS * K9) // 9216 floats per (o,c) weight row

typedef __bf16 v8bf __attribute__((ext_vector_type(8)));
typedef float  v4f  __attribute__((ext_vector_type(4)));
typedef float  f4a  __attribute__((ext_vector_type(4)));              // 16-B aligned float4

__device__ __forceinline__ unsigned short f2bf(float f) {
    union { float f; unsigned int u; } v; v.f = f;
    unsigned int u = v.u;
    return (unsigned short)((u + 0x7FFFu + ((u >> 16) & 1u)) >> 16);
}

// ---------------------------------------------------------------------------
// Pass 1: repack x (fp32 [b][c][34][34]) -> x2 (bf16 [h][w][b][c]).
// Block = (b-pair, h-pair); 272-B contiguous reads per (b,c), float2 loads,
// transposed LDS tile, ushort2 stores.  [unchanged]
// ---------------------------------------------------------------------------
__global__ __launch_bounds__(256) void repack_x(const float* __restrict__ x,
                                                unsigned short* __restrict__ x2) {
    const int bq = blockIdx.x / 17;      // b-pair 0..63
    const int hp = blockIdx.x % 17;      // h-pair 0..16
    const int b0 = bq * 2;
    const int h0 = hp * 2;
    __shared__ unsigned short tile[2][H_][66];   // [hh][w][bb*32+c] (+2 pad)
    const int t = threadIdx.x;

    for (int e = t; e < 2176; e += 256) {
        const int bb  = e / 1088;
        const int rem = e % 1088;
        const int c   = rem / 34;
        const int wp  = rem % 34;        // float2 index within the 68-float run
        const float2 v = *(const float2*)(x +
            ((size_t)((b0 + bb) * C_ + c) * H_ + h0) * H_ + wp * 2);
        const int hh = (wp >= 17) ? 1 : 0;
        const int w  = wp * 2 - hh * 34;
        const int idx = bb * 32 + c;
        tile[hh][w][idx]     = f2bf(v.x);
        tile[hh][w + 1][idx] = f2bf(v.y);
    }
    __syncthreads();

    for (int e = t; e < 2176; e += 256) {
        const int hh  = e / 1088;
        const int rem = e % 1088;
        const int w   = rem >> 5;
        const int i2  = rem & 31;
        ushort2 pk;
        pk.x = tile[hh][w][i2 * 2];
        pk.y = tile[hh][w][i2 * 2 + 1];
        *(ushort2*)(x2 + (size_t)((h0 + hh) * H_ + w) * BC + bq * 64 + i2 * 2) = pk;
    }
}

// ---------------------------------------------------------------------------
// Main (v6): run-length-maximized gather.  256 blocks x 512 threads.
// Block = (i, j-half of 16, o-quarter of 16).  Weight slice per pl (=o_l*32+c)
// is 576 B CONTIGUOUS (16 j x 9 taps), 64-B aligned (posbase*36B, 576=9*64)
// -> exactly 9 full lines per pl, ZERO over-fetch.  Whole slice parked in
// 144 KB LDS bf16 image (one block/CU; occupancy low BY DESIGN — gather BW
// was measured invariant to TLP in r2-r4, so we bet on run length instead).
// LDS layout: 144 d-rows (d = jj*9+tap) x 512 cols, col = swizzle(pl,d4) =
//   ((pl>>3) ^ (d4&7))*8 + (pl&7),  d4 = d>>2  (same family as v2).
// Staging: 4608 quad-tasks (pl, q4: 4 consecutive dwordx4), 9/thread in 3
// batches of 12 loads (d4-fastest lane order -> 9-lane 144-B coalesced
// groups; full 576-B row requested within one batch window).
// Compute: two j-octet passes from LDS; one barrier total.
// Epilogue: fp32 out[b][o][pos] + bias; per (b,o) each jh writes an aligned
// 32-B half-line and jh=0/1 complete the 64-B line within the same block.
// ---------------------------------------------------------------------------
__global__ __launch_bounds__(512, 2) void lc_fused5(const unsigned short* __restrict__ x2,
                                                    const float* __restrict__ weight,
                                                    const float* __restrict__ bias,
                                                    float* __restrict__ out) {
    __shared__ __align__(16) unsigned short Wl[144 * 512];  // 147,456 B

    const int bid = blockIdx.x;
    const int lb  = (bid & 7) * 32 + (bid >> 3);   // bijective (256 % 8 == 0)
    const int i   = lb >> 3;           // 0..31
    const int jq  = (lb >> 2) & 1;     // 0..1  (16-j half)
    const int oq  = lb & 3;            // 0..3  (16-o quarter)
    const int j0  = jq * 16;
    const int o0  = oq * 16;
    const int posbase = i * 32 + j0;   // multiple of 16 -> 64-B line ownership
    const int t = threadIdx.x;         // 0..511

    // ---- stage: 512 pl x 144 floats contiguous; 4608 (pl,q4) quad-tasks ----
    const float* wbase = weight + ((size_t)(o0 * C_) * NPOS + posbase) * K9;
#pragma unroll
    for (int r = 0; r < 3; ++r) {
        f4a v[3][4];
#pragma unroll
        for (int m = 0; m < 3; ++m) {
            const int Q  = (r * 3 + m) * 512 + t;   // 0..4607
            const int pl = Q / 9;
            const int q4 = Q % 9;
            const float* src = wbase + (size_t)pl * NPK + q4 * 16;
#pragma unroll
            for (int s = 0; s < 4; ++s)
                v[m][s] = *(const f4a*)(src + s * 4);
        }
#pragma unroll
        for (int m = 0; m < 3; ++m) {
            const int Q  = (r * 3 + m) * 512 + t;
            const int pl = Q / 9;
            const int q4 = Q % 9;
#pragma unroll
            for (int s = 0; s < 4; ++s) {
                const int d4  = q4 * 4 + s;                      // 0..35
                const int col = ((pl >> 3) ^ (d4 & 7)) * 8 + (pl & 7);
#pragma unroll
                for (int u = 0; u < 4; ++u)
                    Wl[(d4 * 4 + u) * 512 + col] = f2bf(v[m][s][u]);
            }
        }
    }
    __syncthreads();

    const int wv = t >> 6;      // wave -> 16-b band (8 waves)
    const int l  = t & 63;
    const int lm = l & 15;      // o_local (B n-index) / b_local row group
    const int q  = l >> 4;

#pragma unroll
    for (int jh = 0; jh < 2; ++jh) {
        v4f acc[8];
#pragma unroll
        for (int a = 0; a < 8; ++a) acc[a] = (v4f){0.f, 0.f, 0.f, 0.f};

#pragma unroll
        for (int kh = 0; kh < 3; ++kh) {
            v8bf ax[10];
            const int rowbase = (i + kh) * H_ + j0 + jh * 8;
#pragma unroll
            for (int w6 = 0; w6 < 10; ++w6) {
                const unsigned short* xrow = x2 + (size_t)(rowbase + w6) * BC;
                ax[w6] = *(const v8bf*)(xrow + (wv * 16 + lm) * C_ + q * 8);
            }
#pragma unroll
            for (int kw = 0; kw < 3; ++kw) {
                const int tap = kh * 3 + kw;
#pragma unroll
                for (int jj = 0; jj < 8; ++jj) {
                    const int jk = (jh * 8 + jj) * K9 + tap;     // d-row 0..143
                    const int gc = ((lm * 4 + q) ^ ((jk >> 2) & 7)) * 8;
                    const v8bf bfr = *(const v8bf*)&Wl[jk * 512 + gc];
                    acc[jj] = __builtin_amdgcn_mfma_f32_16x16x32_bf16(
                        ax[kw + jj], bfr, acc[jj], 0, 0, 0);
                }
            }
        }

        // ---- epilogue jh: fp32 out + bias; 32-B aligned 32-B runs ----
        const float* bp = bias + (size_t)(o0 + lm) * NPOS + posbase + jh * 8;
        const f4a bv0 = *(const f4a*)bp;
        const f4a bv1 = *(const f4a*)(bp + 4);
#pragma unroll
        for (int r2 = 0; r2 < 4; ++r2) {
            const int b = wv * 16 + q * 4 + r2;
            float* op = out + ((size_t)b * O_ + (o0 + lm)) * NPOS + posbase + jh * 8;
            f4a lo = {acc[0][r2] + bv0[0], acc[1][r2] + bv0[1],
                      acc[2][r2] + bv0[2], acc[3][r2] + bv0[3]};
            f4a hi = {acc[4][r2] + bv1[0], acc[5][r2] + bv1[1],
                      acc[6][r2] + bv1[2], acc[7][r2] + bv1[3]};
            *(f4a*)op       = lo;
            *(f4a*)(op + 4) = hi;
        }
    }
}

// ---------------------------------------------------------------------------
// Fallback (no workspace): per-pos kernel gathering straight from fp32.
// ---------------------------------------------------------------------------
__global__ __launch_bounds__(256) void lc_fallback(const float* __restrict__ x,
                                                   const float* __restrict__ weight,
                                                   const float* __restrict__ bias,
                                                   float* __restrict__ out) {
    const int pos = blockIdx.x;
    const int i = pos >> 5, j = pos & 31;
    const int t  = threadIdx.x;
    const int wv = t >> 6;
    const int l  = t & 63;
    const int lm = l & 15;
    const int q  = l >> 4;

    float bv[4];
#pragma unroll
    for (int nt = 0; nt < 4; ++nt)
        bv[nt] = bias[(size_t)(nt * 16 + lm) * NPOS + pos];

    v4f acc[2][4];
#pragma unroll
    for (int a = 0; a < 2; ++a)
#pragma unroll
        for (int n = 0; n < 4; ++n) acc[a][n] = (v4f){0.f, 0.f, 0.f, 0.f};

    for (int k = 0; k < K9; ++k) {
        const int kh = k / 3, kw = k % 3;
        v8bf af[2], bfr[4];
#pragma unroll
        for (int mt = 0; mt < 2; ++mt) {
            const int b = wv * 32 + mt * 16 + lm;
            union { v8bf v; unsigned short s[8]; } u;
#pragma unroll
            for (int cc = 0; cc < 8; ++cc)
                u.s[cc] = f2bf(x[(((size_t)b * C_ + q * 8 + cc) * H_ + (i + kh)) * H_ + (j + kw)]);
            af[mt] = u.v;
        }
#pragma unroll
        for (int nt = 0; nt < 4; ++nt) {
            union { v8bf v; unsigned short s[8]; } u;
#pragma unroll
            for (int cc = 0; cc < 8; ++cc) {
                const int p = (nt * 16 + lm) * C_ + q * 8 + cc;
                u.s[cc] = f2bf(weight[((size_t)p * NPOS + pos) * K9 + k]);
            }
            bfr[nt] = u.v;
        }
#pragma unroll
        for (int mt = 0; mt < 2; ++mt)
#pragma unroll
            for (int nt = 0; nt < 4; ++nt)
                acc[mt][nt] = __builtin_amdgcn_mfma_f32_16x16x32_bf16(
                    af[mt], bfr[nt], acc[mt][nt], 0, 0, 0);
    }
#pragma unroll
    for (int mt = 0; mt < 2; ++mt)
#pragma unroll
        for (int nt = 0; nt < 4; ++nt) {
            const int o = nt * 16 + lm;
#pragma unroll
            for (int r = 0; r < 4; ++r) {
                const int b = wv * 32 + mt * 16 + q * 4 + r;
                out[(size_t)(b * O_ + o) * NPOS + pos] = acc[mt][nt][r] + bv[nt];
            }
        }
}

// ---------------------------------------------------------------------------
extern "C" void kernel_launch(void* const* d_in, const int* in_sizes, int n_in,
                              void* d_out, int out_size, void* d_ws, size_t ws_size,
                              hipStream_t stream) {
    const float* x      = (const float*)d_in[0];
    const float* weight = (const float*)d_in[1];
    const float* bias   = (const float*)d_in[2];
    float* out          = (float*)d_out;

    const size_t X2B = (size_t)H_ * H_ * BC * sizeof(unsigned short);     // 9,469,952

    if (ws_size >= X2B) {
        unsigned short* x2 = (unsigned short*)d_ws;
        repack_x<<<64 * 17, 256, 0, stream>>>(x, x2);
        lc_fused5<<<256, 512, 0, stream>>>(x2, weight, bias, out);
    } else {
        lc_fallback<<<NPOS, 256, 0, stream>>>(x, weight, bias, out);
    }
}